// Round 5
// baseline (513.837 us; speedup 1.0000x reference)
//
#include <hip/hip_runtime.h>
#include <cstdint>

typedef unsigned short u16;
typedef short bf16x8 __attribute__((ext_vector_type(8)));
typedef float floatx4 __attribute__((ext_vector_type(4)));

#define BB 2048
#define UU 1024
#define HUx 256
#define O_H  0
#define O_C  (BB*UU)
#define O_HO (2*BB*UU)
#define O_HC (2*BB*UU + BB*HUx)

__device__ __forceinline__ float bf2f(u16 u) {
    union { uint32_t i; float f; } v; v.i = ((uint32_t)u) << 16; return v.f;
}
__device__ __forceinline__ u16 f2bf(float f) {
    union { float f; uint32_t i; } v; v.f = f;
    uint32_t r = v.i + 0x7fffu + ((v.i >> 16) & 1u);
    return (u16)(r >> 16);
}
__device__ __forceinline__ float sigf(float x) { return 1.f / (1.f + expf(-x)); }
__device__ __forceinline__ float ldmix(const void* p, size_t i, int isbf) {
    return isbf ? bf2f(((const u16*)p)[i]) : ((const float*)p)[i];
}

// async global->LDS, 16B per lane; LDS dest = uniform base + lane*16
__device__ __forceinline__ void gll16(const u16* g, u16* l) {
    __builtin_amdgcn_global_load_lds((const __attribute__((address_space(1))) void*)g,
                                     (__attribute__((address_space(3))) void*)l, 16, 0, 0);
}
// stage tile rows x 64 bf16 (row-major [rows][64]) from src(row0, k0), row stride ldK.
// chunk = 8 rows = 1 KB; chunks distributed across the block's 4 waves.
__device__ __forceinline__ void stage(u16* lds, const u16* src, int row0, int ldK,
                                      int k0, int rows, int wave, int lane) {
    int nch = rows >> 3;
    for (int c = wave; c < nch; c += 4) {
        const u16* g = src + (size_t)(row0 + (c << 3) + (lane >> 3)) * ldK + k0 + ((lane & 7) << 3);
        gll16(g, lds + (c << 9));
    }
}

// ---------------- dtype detection (1 = bf16, 0 = fp32) ----------------
__global__ void detect_dtype(const u16* __restrict__ raw, int* __restrict__ flag) {
    u16 u = raw[2 * threadIdx.x];
    int e = (u >> 7) & 0xFF;
    unsigned long long m = __ballot(e >= 100 && e <= 134);
    if (threadIdx.x == 0) *flag = (__popcll(m) >= 32) ? 1 : 0;
}

// ---------------- input -> bf16 hi (+ optional lo residual) planes ----------------
__global__ void cvt_in2(const void* __restrict__ src, u16* __restrict__ hi,
                        u16* __restrict__ lo, int n8, const int* __restrict__ flag) {
    int i = blockIdx.x * 256 + threadIdx.x;
    if (i >= n8) return;
    if (*flag) {
        ((bf16x8*)hi)[i] = ((const bf16x8*)src)[i];
        if (lo) { bf16x8 z = {}; ((bf16x8*)lo)[i] = z; }
    } else {
        const float* s = (const float*)src + (size_t)i * 8;
        #pragma unroll
        for (int j = 0; j < 8; j++) {
            float v = s[j];
            u16 h = f2bf(v);
            hi[(size_t)i * 8 + j] = h;
            if (lo) lo[(size_t)i * 8 + j] = f2bf(v - bf2f(h));
        }
    }
}

// ---------------- transpose(+convert) hi (+ optional lo): out[c*ostride+ocol+r]=in[r*C+c] ----------------
__global__ void transpose_cvt2(const void* __restrict__ in, u16* __restrict__ out_hi,
                               u16* __restrict__ out_lo, int R, int C, int ostride, int ocol,
                               const int* __restrict__ flag) {
    __shared__ u16 th[32][33];
    __shared__ u16 tl[32][33];
    int isbf = *flag;
    int c0 = blockIdx.x * 32, r0 = blockIdx.y * 32;
    int tx = threadIdx.x, ty = threadIdx.y;  // block (32,8)
    #pragma unroll
    for (int i = 0; i < 32; i += 8) {
        size_t idx = (size_t)(r0 + ty + i) * C + c0 + tx;
        u16 h; u16 l = 0;
        if (isbf) {
            h = ((const u16*)in)[idx];
        } else {
            float v = ((const float*)in)[idx];
            h = f2bf(v);
            l = f2bf(v - bf2f(h));
        }
        th[ty + i][tx] = h;
        tl[ty + i][tx] = l;
    }
    __syncthreads();
    #pragma unroll
    for (int i = 0; i < 32; i += 8) {
        size_t o = (size_t)(c0 + ty + i) * ostride + ocol + r0 + tx;
        out_hi[o] = th[tx][ty + i];
        if (out_lo) out_lo[o] = tl[tx][ty + i];
    }
}

// ---------------- hyper GEMM: z[2048,1024] = (xh+xl)@Wx + mh@Wm + hh@Wh ----------------
// block 128M x 64N, 4 waves each 64x32; BK=64; async staging
__global__ __launch_bounds__(256) void gemm_hyper(const u16* __restrict__ xh,
                                                  const u16* __restrict__ xl,
                                                  const u16* __restrict__ mh,
                                                  const u16* __restrict__ hh,
                                                  const u16* __restrict__ BT,
                                                  float* __restrict__ z) {
    __shared__ __align__(16) u16 S[12288];  // sA 128x64 (8192) + sB 64x64 (4096)
    int tid = threadIdx.x, lane = tid & 63, wave = tid >> 6;
    int wm = (wave & 1) * 64, wn = (wave >> 1) * 32;
    int bm = blockIdx.y * 128, bn = blockIdx.x * 64;
    floatx4 acc[4][2] = {};
    int mr = lane & 15, kq = (lane >> 4) * 8;
    #pragma unroll 1
    for (int ph = 0; ph < 4; ph++) {
        const u16* Ap = (ph == 0) ? xh : (ph == 1) ? xl : (ph == 2) ? mh : hh;
        int ldA = (ph == 3) ? 256 : 1024;
        int K   = (ph == 3) ? 256 : 1024;
        int koff = (ph == 3) ? 2048 : (ph == 2) ? 1024 : 0;
        for (int k0 = 0; k0 < K; k0 += 64) {
            stage(S, Ap, bm, ldA, k0, 128, wave, lane);
            stage(S + 8192, BT, bn, 2304, koff + k0, 64, wave, lane);
            __syncthreads();
            #pragma unroll
            for (int ks = 0; ks < 2; ks++) {
                int kc = ks * 32 + kq;
                bf16x8 a[4], b[2];
                #pragma unroll
                for (int t = 0; t < 4; t++) a[t] = *(const bf16x8*)&S[(wm + t * 16 + mr) * 64 + kc];
                #pragma unroll
                for (int t = 0; t < 2; t++) b[t] = *(const bf16x8*)&S[8192 + (wn + t * 16 + mr) * 64 + kc];
                #pragma unroll
                for (int tm = 0; tm < 4; tm++)
                    #pragma unroll
                    for (int tn = 0; tn < 2; tn++)
                        acc[tm][tn] = __builtin_amdgcn_mfma_f32_16x16x32_bf16(a[tm], b[tn], acc[tm][tn], 0, 0, 0);
            }
            __syncthreads();
        }
    }
    #pragma unroll
    for (int tm = 0; tm < 4; tm++)
        #pragma unroll
        for (int tn = 0; tn < 2; tn++) {
            int col = bn + wn + tn * 16 + (lane & 15);
            #pragma unroll
            for (int rr = 0; rr < 4; rr++) {
                int row = bm + wm + tm * 16 + (lane >> 4) * 4 + rr;
                z[(size_t)row * 1024 + col] = acc[tm][tn][rr];
            }
        }
}

// ---------------- hyper LSTM cell; hyper_out -> bf16 hi + lo residual ----------------
__global__ void hyper_cell(const float* __restrict__ z, const void* __restrict__ hyper_c,
                           const void* __restrict__ hyper_bias, void* __restrict__ out,
                           u16* __restrict__ ho_hi, u16* __restrict__ ho_lo,
                           const int* __restrict__ flag) {
    int isbf = *flag;
    int t = blockIdx.x * 256 + threadIdx.x;
    int k = t & 255;
    const float* zr = z + (size_t)(t >> 8) * 1024;
    float hi = zr[k]       + ldmix(hyper_bias, k, isbf);
    float hf = zr[k + 256] + ldmix(hyper_bias, k + 256, isbf);
    float hg = zr[k + 512] + ldmix(hyper_bias, k + 512, isbf);
    float ho = zr[k + 768] + ldmix(hyper_bias, k + 768, isbf);
    float c  = ldmix(hyper_c, t, isbf);
    float cn = sigf(hf) * c + sigf(hi) * tanhf(hg);
    float hout = sigf(ho) * tanhf(cn);
    u16 hu = f2bf(hout);
    ho_hi[t] = hu;
    ho_lo[t] = f2bf(hout - bf2f(hu));
    if (isbf) {
        ((u16*)out)[O_HO + t] = hu;
        ((u16*)out)[O_HC + t] = f2bf(cn);
    } else {
        ((float*)out)[O_HO + t] = hout;
        ((float*)out)[O_HC + t] = cn;
    }
}

// ---------------- fused gates GEMM: block 64M x 128N, 4 waves each 32x64, BK=64, async ----------------
// phase1: apx = (xh+xl)@kT, aph = mh@rkT  (K=1024)
// phase2a: d_* += hohi @ [Whi|Wlo]  (K-concat 512);  phase2b: d_* += holo @ Whi (K=256)
__global__ __launch_bounds__(256) void mega_gates(
    const u16* __restrict__ xh, const u16* __restrict__ xl, const u16* __restrict__ mh,
    const u16* __restrict__ ho_hi, const u16* __restrict__ ho_lo,
    const u16* __restrict__ kT, const u16* __restrict__ rkT,
    const u16* __restrict__ dxc, const u16* __restrict__ dhc, const u16* __restrict__ dbc,
    const void* __restrict__ bias, const void* __restrict__ dx_b,
    const void* __restrict__ dh_b, const void* __restrict__ db_b,
    u16* __restrict__ gp_hi, u16* __restrict__ gp_lo, const int* __restrict__ flag) {
    __shared__ __align__(16) u16 S[28672];  // 56 KB
    int isbf = *flag;
    int tid = threadIdx.x, lane = tid & 63, wave = tid >> 6;
    int wm = (wave & 1) * 32, wn = (wave >> 1) * 64;
    int bm = blockIdx.y * 64, bn = blockIdx.x * 128;
    floatx4 apx[2][4] = {}, aph[2][4] = {}, adx[2][4] = {}, adh[2][4] = {}, adb[2][4] = {};
    int mr = lane & 15, kq = (lane >> 4) * 8;

    // ---- phase 1: s0=xh(64x64) s1=xl s2=mh @ +0/+4096/+8192; kT(128x64)@+12288, rkT@+20480
    for (int k0 = 0; k0 < 1024; k0 += 64) {
        stage(S,         xh,  bm, 1024, k0, 64,  wave, lane);
        stage(S + 4096,  xl,  bm, 1024, k0, 64,  wave, lane);
        stage(S + 8192,  mh,  bm, 1024, k0, 64,  wave, lane);
        stage(S + 12288, kT,  bn, 1024, k0, 128, wave, lane);
        stage(S + 20480, rkT, bn, 1024, k0, 128, wave, lane);
        __syncthreads();
        #pragma unroll
        for (int ks = 0; ks < 2; ks++) {
            int kc = ks * 32 + kq;
            bf16x8 axh[2], axl[2], amh[2], bk[4], br[4];
            #pragma unroll
            for (int t = 0; t < 2; t++) {
                int ra = (wm + t * 16 + mr) * 64 + kc;
                axh[t] = *(const bf16x8*)&S[ra];
                axl[t] = *(const bf16x8*)&S[4096 + ra];
                amh[t] = *(const bf16x8*)&S[8192 + ra];
            }
            #pragma unroll
            for (int t = 0; t < 4; t++) {
                int rb = (wn + t * 16 + mr) * 64 + kc;
                bk[t] = *(const bf16x8*)&S[12288 + rb];
                br[t] = *(const bf16x8*)&S[20480 + rb];
            }
            #pragma unroll
            for (int tm = 0; tm < 2; tm++)
                #pragma unroll
                for (int tn = 0; tn < 4; tn++) {
                    apx[tm][tn] = __builtin_amdgcn_mfma_f32_16x16x32_bf16(axh[tm], bk[tn], apx[tm][tn], 0, 0, 0);
                    apx[tm][tn] = __builtin_amdgcn_mfma_f32_16x16x32_bf16(axl[tm], bk[tn], apx[tm][tn], 0, 0, 0);
                    aph[tm][tn] = __builtin_amdgcn_mfma_f32_16x16x32_bf16(amh[tm], br[tn], aph[tm][tn], 0, 0, 0);
                }
        }
        __syncthreads();
    }
    // ---- phase 2: A @ +0 (64x64); B1/B2/B3 (128x64) @ +4096/+12288/+20480
    for (int k0 = 0; k0 < 768; k0 += 64) {
        const u16* Ap = (k0 < 512) ? ho_hi : ho_lo;
        int ka = k0 & 255;          // 0..192,0..192,0..192
        int kb = (k0 < 512) ? k0 : (k0 - 512);  // B cols: 0..448 then 0..192 (Whi again)
        stage(S,         Ap,  bm, 256, ka, 64,  wave, lane);
        stage(S + 4096,  dxc, bn, 512, kb, 128, wave, lane);
        stage(S + 12288, dhc, bn, 512, kb, 128, wave, lane);
        stage(S + 20480, dbc, bn, 512, kb, 128, wave, lane);
        __syncthreads();
        #pragma unroll
        for (int ks = 0; ks < 2; ks++) {
            int kc = ks * 32 + kq;
            bf16x8 a[2], bx[4], bh[4], bb[4];
            #pragma unroll
            for (int t = 0; t < 2; t++) a[t] = *(const bf16x8*)&S[(wm + t * 16 + mr) * 64 + kc];
            #pragma unroll
            for (int t = 0; t < 4; t++) {
                int rb = (wn + t * 16 + mr) * 64 + kc;
                bx[t] = *(const bf16x8*)&S[4096 + rb];
                bh[t] = *(const bf16x8*)&S[12288 + rb];
                bb[t] = *(const bf16x8*)&S[20480 + rb];
            }
            #pragma unroll
            for (int tm = 0; tm < 2; tm++)
                #pragma unroll
                for (int tn = 0; tn < 4; tn++) {
                    adx[tm][tn] = __builtin_amdgcn_mfma_f32_16x16x32_bf16(a[tm], bx[tn], adx[tm][tn], 0, 0, 0);
                    adh[tm][tn] = __builtin_amdgcn_mfma_f32_16x16x32_bf16(a[tm], bh[tn], adh[tm][tn], 0, 0, 0);
                    adb[tm][tn] = __builtin_amdgcn_mfma_f32_16x16x32_bf16(a[tm], bb[tn], adb[tm][tn], 0, 0, 0);
                }
        }
        __syncthreads();
    }
    // ---- epilogue
    #pragma unroll
    for (int tm = 0; tm < 2; tm++)
        #pragma unroll
        for (int tn = 0; tn < 4; tn++) {
            int col = bn + wn + tn * 16 + (lane & 15);
            float bv  = ldmix(bias, col, isbf);
            float dxb = ldmix(dx_b, col, isbf);
            float dhb = ldmix(dh_b, col, isbf);
            float dbb = ldmix(db_b, col, isbf);
            #pragma unroll
            for (int rr = 0; rr < 4; rr++) {
                int row = bm + wm + tm * 16 + (lane >> 4) * 4 + rr;
                float px = apx[tm][tn][rr] + bv;
                float ph = aph[tm][tn][rr];
                float dx = adx[tm][tn][rr] + dxb;
                float dh = adh[tm][tn][rr] + dhb;
                float db = adb[tm][tn][rr] + dbb;
                float g = dx * px + dh * ph + db;
                u16 hi = f2bf(g);
                gp_hi[(size_t)row * 4096 + col] = hi;
                gp_lo[(size_t)row * 4096 + col] = f2bf(g - bf2f(hi));
            }
        }
}

// ---------------- LN(4096) -> gates -> c_new -> LN(1024) -> h_new ----------------
__device__ __forceinline__ void block_reduce2(float& a, float& b, float* red) {
    #pragma unroll
    for (int o = 32; o > 0; o >>= 1) {
        a += __shfl_down(a, o, 64);
        b += __shfl_down(b, o, 64);
    }
    int lane = threadIdx.x & 63, w = threadIdx.x >> 6;
    if (lane == 0) { red[w] = a; red[4 + w] = b; }
    __syncthreads();
    a = red[0] + red[1] + red[2] + red[3];
    b = red[4] + red[5] + red[6] + red[7];
    __syncthreads();
}

__global__ __launch_bounds__(256) void ln_main(const u16* __restrict__ gp_hi,
                                               const u16* __restrict__ gp_lo,
                                               const void* __restrict__ main_c,
                                               void* __restrict__ out,
                                               const int* __restrict__ flag) {
    __shared__ float sPre[4096];
    __shared__ float sC[1024];
    __shared__ float red[8];
    int isbf = *flag;
    int b = blockIdx.x, tid = threadIdx.x;
    const u16* gh = gp_hi + (size_t)b * 4096;
    const u16* gl = gp_lo + (size_t)b * 4096;
    float s = 0.f, q = 0.f;
    for (int j = tid; j < 4096; j += 256) {
        float v = bf2f(gh[j]) + bf2f(gl[j]);
        sPre[j] = v; s += v; q += v * v;
    }
    block_reduce2(s, q, red);
    float mean = s * (1.f / 4096.f);
    float var = q * (1.f / 4096.f) - mean * mean;
    float rs = rsqrtf(var + 1e-3f);
    float s2 = 0.f, q2 = 0.f;
    for (int u = tid; u < 1024; u += 256) {
        float gi = (sPre[u] - mean) * rs;
        float gf = (sPre[u + 1024] - mean) * rs;
        float gg = (sPre[u + 2048] - mean) * rs;
        float c = ldmix(main_c, (size_t)b * 1024 + u, isbf);
        float cn = sigf(gf) * c + sigf(gi) * tanhf(gg);
        sC[u] = cn;
        if (isbf) ((u16*)out)[O_C + (size_t)b * 1024 + u] = f2bf(cn);
        else      ((float*)out)[O_C + (size_t)b * 1024 + u] = cn;
        s2 += cn; q2 += cn * cn;
    }
    block_reduce2(s2, q2, red);
    float m2 = s2 * (1.f / 1024.f);
    float v2 = q2 * (1.f / 1024.f) - m2 * m2;
    float rs2 = rsqrtf(v2 + 1e-3f);
    for (int u = tid; u < 1024; u += 256) {
        float go = (sPre[u + 3072] - mean) * rs;
        float hn = sigf(go) * tanhf((sC[u] - m2) * rs2);
        if (isbf) ((u16*)out)[O_H + (size_t)b * 1024 + u] = f2bf(hn);
        else      ((float*)out)[O_H + (size_t)b * 1024 + u] = hn;
    }
}

// ---------------- launcher ----------------
extern "C" void kernel_launch(void* const* d_in, const int* in_sizes, int n_in,
                              void* d_out, int out_size, void* d_ws, size_t ws_size,
                              hipStream_t stream) {
    (void)in_sizes; (void)n_in; (void)out_size; (void)ws_size;
    const void* inputs   = d_in[0];
    const void* main_h   = d_in[1];
    const void* main_c   = d_in[2];
    const void* hyper_h  = d_in[3];
    const void* hyper_c  = d_in[4];
    const void* kernel_w = d_in[5];
    const void* rec_w    = d_in[6];
    const void* bias     = d_in[7];
    const void* hyper_k  = d_in[8];
    const void* hyper_rk = d_in[9];
    const void* hyper_b  = d_in[10];
    const void* dx_w = d_in[11];
    const void* dx_b = d_in[12];
    const void* dh_w = d_in[13];
    const void* dh_b = d_in[14];
    const void* db_w = d_in[15];
    const void* db_b = d_in[16];
    char* ws = (char*)d_ws;

    // workspace layout; total ~59.3 MB (same budget as passing r4)
    int* flag = (int*)ws;
    size_t off = 256;
    u16* xh   = (u16*)(ws + off); off += (size_t)2048 * 1024 * 2;  // 4 MB
    u16* xl   = (u16*)(ws + off); off += (size_t)2048 * 1024 * 2;  // 4 MB
    u16* mh   = (u16*)(ws + off); off += (size_t)2048 * 1024 * 2;  // 4 MB
    u16* hh   = (u16*)(ws + off); off += (size_t)2048 * 256 * 2;   // 1 MB
    u16* hohi = (u16*)(ws + off); off += (size_t)2048 * 256 * 2;   // 1 MB
    u16* holo = (u16*)(ws + off); off += (size_t)2048 * 256 * 2;   // 1 MB
    u16* kT   = (u16*)(ws + off); off += (size_t)4096 * 1024 * 2;  // 8 MB
    u16* rkT  = (u16*)(ws + off); off += (size_t)4096 * 1024 * 2;  // 8 MB
    u16* dxc  = (u16*)(ws + off); off += (size_t)4096 * 512 * 2;   // 4 MB  [Whi|Wlo]
    u16* dhc  = (u16*)(ws + off); off += (size_t)4096 * 512 * 2;   // 4 MB
    u16* dbc  = (u16*)(ws + off); off += (size_t)4096 * 512 * 2;   // 4 MB
    char* region = ws + off;  // 16 MB, double-used
    u16* BTh = (u16*)region;                                   // [1024,2304] 4.5 MB
    float* zbuf = (float*)(region + (size_t)1024 * 2304 * 2);  // [2048,1024] 8 MB
    u16* gphi = (u16*)region;                                  // [2048,4096] 8 MB (after hyper)
    u16* gplo = (u16*)(region + (size_t)2048 * 4096 * 2);      // 8 MB

    detect_dtype<<<1, 64, 0, stream>>>((const u16*)inputs, flag);

    cvt_in2<<<1024, 256, 0, stream>>>(inputs, xh, xl, 262144, flag);
    cvt_in2<<<1024, 256, 0, stream>>>(main_h, mh, nullptr, 262144, flag);
    cvt_in2<<<256, 256, 0, stream>>>(hyper_h, hh, nullptr, 65536, flag);

    dim3 tblk(32, 8);
    transpose_cvt2<<<dim3(32, 64), tblk, 0, stream>>>(hyper_k, BTh, nullptr, 2048, 1024, 2304, 0, flag);
    transpose_cvt2<<<dim3(32, 8),  tblk, 0, stream>>>(hyper_rk, BTh, nullptr, 256, 1024, 2304, 2048, flag);
    transpose_cvt2<<<dim3(128, 32), tblk, 0, stream>>>(kernel_w, kT, nullptr, 1024, 4096, 1024, 0, flag);
    transpose_cvt2<<<dim3(128, 32), tblk, 0, stream>>>(rec_w, rkT, nullptr, 1024, 4096, 1024, 0, flag);
    // d-weights packed K-concat: hi at cols 0..255, lo at cols 256..511 (ostride 512)
    transpose_cvt2<<<dim3(128, 8),  tblk, 0, stream>>>(dx_w, dxc, dxc + 256, 256, 4096, 512, 0, flag);
    transpose_cvt2<<<dim3(128, 8),  tblk, 0, stream>>>(dh_w, dhc, dhc + 256, 256, 4096, 512, 0, flag);
    transpose_cvt2<<<dim3(128, 8),  tblk, 0, stream>>>(db_w, dbc, dbc + 256, 256, 4096, 512, 0, flag);

    gemm_hyper<<<dim3(16, 16), 256, 0, stream>>>(xh, xl, mh, hh, BTh, zbuf);
    hyper_cell<<<2048, 256, 0, stream>>>(zbuf, hyper_c, hyper_b, d_out, hohi, holo, flag);
    // BTh/zbuf dead; gphi/gplo overwrite region
    mega_gates<<<dim3(32, 32), 256, 0, stream>>>(xh, xl, mh, hohi, holo, kT, rkT,
                                                 dxc, dhc, dbc,
                                                 bias, dx_b, dh_b, db_b, gphi, gplo, flag);
    ln_main<<<2048, 256, 0, stream>>>(gphi, gplo, main_c, d_out, flag);
}

// Round 7
// 470.178 us; speedup vs baseline: 1.0929x; 1.0929x over previous
//
#include <hip/hip_runtime.h>
#include <cstdint>

typedef unsigned short u16;
typedef short bf16x8 __attribute__((ext_vector_type(8)));
typedef float floatx4 __attribute__((ext_vector_type(4)));

#define BB 2048
#define UU 1024
#define HUx 256
#define O_H  0
#define O_C  (BB*UU)
#define O_HO (2*BB*UU)
#define O_HC (2*BB*UU + BB*HUx)
#define MFMA16 __builtin_amdgcn_mfma_f32_16x16x32_bf16

__device__ __forceinline__ float bf2f(u16 u) {
    union { uint32_t i; float f; } v; v.i = ((uint32_t)u) << 16; return v.f;
}
__device__ __forceinline__ float u2f(uint32_t u) {
    union { uint32_t i; float f; } v; v.i = u; return v.f;
}
__device__ __forceinline__ u16 f2bf(float f) {
    union { float f; uint32_t i; } v; v.f = f;
    uint32_t r = v.i + 0x7fffu + ((v.i >> 16) & 1u);
    return (u16)(r >> 16);
}
__device__ __forceinline__ float sigf(float x) { return 1.f / (1.f + expf(-x)); }
__device__ __forceinline__ float ldmix(const void* p, size_t i, int isbf) {
    return isbf ? bf2f(((const u16*)p)[i]) : ((const float*)p)[i];
}

// sync staged copy: rows x 32 bf16 tile from src(row0.., k0..) into padded LDS [rows][40]
// stride 40 u16 = 80 B (16B-aligned rows, 20-bank stride -> even bank spread)
__device__ __forceinline__ void stage_sync(u16* lds, const u16* src, int row0, int ldK,
                                           int k0, int rows, int tid) {
    for (int v = tid; v < rows * 4; v += 256) {
        int r = v >> 2, c = (v & 3) * 8;
        bf16x8 d = *(const bf16x8*)(src + (size_t)(row0 + r) * ldK + k0 + c);
        *(bf16x8*)&lds[r * 40 + c] = d;
    }
}

// ---------------- dtype detection (1 = bf16, 0 = fp32) ----------------
__global__ void detect_dtype(const u16* __restrict__ raw, int* __restrict__ flag) {
    u16 u = raw[2 * threadIdx.x];
    int e = (u >> 7) & 0xFF;
    unsigned long long m = __ballot(e >= 100 && e <= 134);
    if (threadIdx.x == 0) *flag = (__popcll(m) >= 32) ? 1 : 0;
}

// ---------------- merged input conversion: inputs->xh/xl, main_h->mh, hyper_h->hh ----------------
__global__ void cvt_all(const void* __restrict__ xs, const void* __restrict__ ms,
                        const void* __restrict__ hs, u16* __restrict__ xh, u16* __restrict__ xl,
                        u16* __restrict__ mh, u16* __restrict__ hh, const int* __restrict__ flag) {
    int i = blockIdx.x * 256 + threadIdx.x;
    int isbf = *flag;
    if (i < 262144) {
        if (isbf) {
            ((bf16x8*)xh)[i] = ((const bf16x8*)xs)[i];
            bf16x8 z = {}; ((bf16x8*)xl)[i] = z;
        } else {
            const float* s = (const float*)xs + (size_t)i * 8;
            #pragma unroll
            for (int j = 0; j < 8; j++) {
                float v = s[j]; u16 h = f2bf(v);
                xh[(size_t)i * 8 + j] = h;
                xl[(size_t)i * 8 + j] = f2bf(v - bf2f(h));
            }
        }
    } else if (i < 524288) {
        int t = i - 262144;
        if (isbf) ((bf16x8*)mh)[t] = ((const bf16x8*)ms)[t];
        else {
            const float* s = (const float*)ms + (size_t)t * 8;
            #pragma unroll
            for (int j = 0; j < 8; j++) mh[(size_t)t * 8 + j] = f2bf(s[j]);
        }
    } else {
        int t = i - 524288;  // < 65536
        if (isbf) ((bf16x8*)hh)[t] = ((const bf16x8*)hs)[t];
        else {
            const float* s = (const float*)hs + (size_t)t * 8;
            #pragma unroll
            for (int j = 0; j < 8; j++) hh[(size_t)t * 8 + j] = f2bf(s[j]);
        }
    }
}

// ---------------- transpose(+convert) hi (+ optional lo): out[c*ostride+ocol+r]=in[r*C+c] ----------------
__global__ void transpose_cvt2(const void* __restrict__ in, u16* __restrict__ out_hi,
                               u16* __restrict__ out_lo, int R, int C, int ostride, int ocol,
                               const int* __restrict__ flag) {
    __shared__ u16 th[32][33];
    __shared__ u16 tl[32][33];
    int isbf = *flag;
    int c0 = blockIdx.x * 32, r0 = blockIdx.y * 32;
    int tx = threadIdx.x, ty = threadIdx.y;  // block (32,8)
    #pragma unroll
    for (int i = 0; i < 32; i += 8) {
        size_t idx = (size_t)(r0 + ty + i) * C + c0 + tx;
        u16 h; u16 l = 0;
        if (isbf) h = ((const u16*)in)[idx];
        else { float v = ((const float*)in)[idx]; h = f2bf(v); l = f2bf(v - bf2f(h)); }
        th[ty + i][tx] = h;
        tl[ty + i][tx] = l;
    }
    __syncthreads();
    #pragma unroll
    for (int i = 0; i < 32; i += 8) {
        size_t o = (size_t)(c0 + ty + i) * ostride + ocol + r0 + tx;
        out_hi[o] = th[tx][ty + i];
        if (out_lo) out_lo[o] = tl[tx][ty + i];
    }
}

// ---------------- d-weight transpose, all 3 in one launch; K-concat layouts ----------------
// split3=1: out = [Whi | Whi | Wlo] (ostride 768); split3=0: [Whi | Wlo] (ostride 512)
__global__ void transpose_d(const void* __restrict__ d0, const void* __restrict__ d1,
                            const void* __restrict__ d2, u16* __restrict__ o0,
                            u16* __restrict__ o1, u16* __restrict__ o2,
                            int ostride, int split3, const int* __restrict__ flag) {
    __shared__ u16 th[32][33];
    __shared__ u16 tl[32][33];
    const void* in = (blockIdx.z == 0) ? d0 : (blockIdx.z == 1) ? d1 : d2;
    u16* out = (blockIdx.z == 0) ? o0 : (blockIdx.z == 1) ? o1 : o2;
    int isbf = *flag;
    int c0 = blockIdx.x * 32, r0 = blockIdx.y * 32;  // in [256, 4096]
    int tx = threadIdx.x, ty = threadIdx.y;
    #pragma unroll
    for (int i = 0; i < 32; i += 8) {
        size_t idx = (size_t)(r0 + ty + i) * 4096 + c0 + tx;
        u16 h; u16 l = 0;
        if (isbf) h = ((const u16*)in)[idx];
        else { float v = ((const float*)in)[idx]; h = f2bf(v); l = f2bf(v - bf2f(h)); }
        th[ty + i][tx] = h;
        tl[ty + i][tx] = l;
    }
    __syncthreads();
    #pragma unroll
    for (int i = 0; i < 32; i += 8) {
        size_t o = (size_t)(c0 + ty + i) * ostride + r0 + tx;
        u16 hv = th[tx][ty + i], lv = tl[tx][ty + i];
        out[o] = hv;
        if (split3) { out[o + 256] = hv; out[o + 512] = lv; }
        else        { out[o + 256] = lv; }
    }
}

// ---------------- hyper GEMM: z = (xh+xl)@Wx + mh@Wm + hh@Wh ; padded sync staging ----------------
// block 128M x 64N, waves 2x2, wave 64x32
__global__ __launch_bounds__(256) void gemm_hyper(const u16* __restrict__ xh,
                                                  const u16* __restrict__ xl,
                                                  const u16* __restrict__ mh,
                                                  const u16* __restrict__ hh,
                                                  const u16* __restrict__ BT,
                                                  float* __restrict__ z) {
    __shared__ __align__(16) u16 sA[128 * 40];
    __shared__ __align__(16) u16 sB[64 * 40];
    int tid = threadIdx.x, lane = tid & 63, wave = tid >> 6;
    int wm = (wave & 1) * 64, wn = (wave >> 1) * 32;
    int bm = blockIdx.y * 128, bn = blockIdx.x * 64;
    floatx4 acc[4][2] = {};
    int mr = lane & 15, kq = (lane >> 4) * 8;
    #pragma unroll 1
    for (int ph = 0; ph < 4; ph++) {
        const u16* Ap = (ph == 0) ? xh : (ph == 1) ? xl : (ph == 2) ? mh : hh;
        int ldA  = (ph == 3) ? 256 : 1024;
        int K    = (ph == 3) ? 256 : 1024;
        int koff = (ph == 3) ? 2048 : (ph == 2) ? 1024 : 0;
        for (int k0 = 0; k0 < K; k0 += 32) {
            stage_sync(sA, Ap, bm, ldA, k0, 128, tid);
            stage_sync(sB, BT, bn, 2304, koff + k0, 64, tid);
            __syncthreads();
            bf16x8 a[4], b[2];
            #pragma unroll
            for (int t = 0; t < 4; t++) a[t] = *(const bf16x8*)&sA[(wm + t * 16 + mr) * 40 + kq];
            #pragma unroll
            for (int t = 0; t < 2; t++) b[t] = *(const bf16x8*)&sB[(wn + t * 16 + mr) * 40 + kq];
            #pragma unroll
            for (int tm = 0; tm < 4; tm++)
                #pragma unroll
                for (int tn = 0; tn < 2; tn++)
                    acc[tm][tn] = MFMA16(a[tm], b[tn], acc[tm][tn], 0, 0, 0);
            __syncthreads();
        }
    }
    #pragma unroll
    for (int tm = 0; tm < 4; tm++)
        #pragma unroll
        for (int tn = 0; tn < 2; tn++) {
            int col = bn + wn + tn * 16 + (lane & 15);
            #pragma unroll
            for (int rr = 0; rr < 4; rr++) {
                int row = bm + wm + tm * 16 + (lane >> 4) * 4 + rr;
                z[(size_t)row * 1024 + col] = acc[tm][tn][rr];
            }
        }
}

// ---------------- hyper LSTM cell; writes hoc K-concat plane(s) ----------------
// hoc row layout: [hi | lo] (stride 512) or [hi | lo | hi] (stride 768, third=1)
__global__ void hyper_cell(const float* __restrict__ z, const void* __restrict__ hyper_c,
                           const void* __restrict__ hyper_bias, void* __restrict__ out,
                           u16* __restrict__ hoc, int stride, int third,
                           const int* __restrict__ flag) {
    int isbf = *flag;
    int t = blockIdx.x * 256 + threadIdx.x;
    int k = t & 255;
    const float* zr = z + (size_t)(t >> 8) * 1024;
    float hi = zr[k]       + ldmix(hyper_bias, k, isbf);
    float hf = zr[k + 256] + ldmix(hyper_bias, k + 256, isbf);
    float hg = zr[k + 512] + ldmix(hyper_bias, k + 512, isbf);
    float ho = zr[k + 768] + ldmix(hyper_bias, k + 768, isbf);
    float c  = ldmix(hyper_c, t, isbf);
    float cn = sigf(hf) * c + sigf(hi) * tanhf(hg);
    float hout = sigf(ho) * tanhf(cn);
    u16 hu = f2bf(hout);
    u16 lu = f2bf(hout - bf2f(hu));
    size_t base = (size_t)(t >> 8) * stride + k;
    hoc[base] = hu;
    hoc[base + 256] = lu;
    if (third) hoc[base + 512] = hu;
    if (isbf) {
        ((u16*)out)[O_HO + t] = hu;
        ((u16*)out)[O_HC + t] = f2bf(cn);
    } else {
        ((float*)out)[O_HO + t] = hout;
        ((float*)out)[O_HC + t] = cn;
    }
}

// ---------------- SPLIT kernel P: px = (xh+xl) @ kT^T  fp32 out ----------------
// block 128x128, waves 2x2, wave 64x64, 1 acc set
__global__ __launch_bounds__(256) void proj_px(const u16* __restrict__ xh,
                                               const u16* __restrict__ xl,
                                               const u16* __restrict__ kT,
                                               float* __restrict__ px) {
    __shared__ __align__(16) u16 sXH[128 * 40];
    __shared__ __align__(16) u16 sXL[128 * 40];
    __shared__ __align__(16) u16 sB[128 * 40];
    int tid = threadIdx.x, lane = tid & 63, wave = tid >> 6;
    int wm = (wave & 1) * 64, wn = (wave >> 1) * 64;
    int bm = blockIdx.y * 128, bn = blockIdx.x * 128;
    floatx4 acc[4][4] = {};
    int mr = lane & 15, kq = (lane >> 4) * 8;
    for (int k0 = 0; k0 < 1024; k0 += 32) {
        stage_sync(sXH, xh, bm, 1024, k0, 128, tid);
        stage_sync(sXL, xl, bm, 1024, k0, 128, tid);
        stage_sync(sB,  kT, bn, 1024, k0, 128, tid);
        __syncthreads();
        bf16x8 ah[4], al[4], b[4];
        #pragma unroll
        for (int t = 0; t < 4; t++) {
            int ra = (wm + t * 16 + mr) * 40 + kq;
            ah[t] = *(const bf16x8*)&sXH[ra];
            al[t] = *(const bf16x8*)&sXL[ra];
            b[t]  = *(const bf16x8*)&sB[(wn + t * 16 + mr) * 40 + kq];
        }
        #pragma unroll
        for (int tm = 0; tm < 4; tm++)
            #pragma unroll
            for (int tn = 0; tn < 4; tn++) {
                acc[tm][tn] = MFMA16(ah[tm], b[tn], acc[tm][tn], 0, 0, 0);
                acc[tm][tn] = MFMA16(al[tm], b[tn], acc[tm][tn], 0, 0, 0);
            }
        __syncthreads();
    }
    #pragma unroll
    for (int tm = 0; tm < 4; tm++)
        #pragma unroll
        for (int tn = 0; tn < 4; tn++) {
            int col = bn + wn + tn * 16 + (lane & 15);
            #pragma unroll
            for (int rr = 0; rr < 4; rr++) {
                int row = bm + wm + tm * 16 + (lane >> 4) * 4 + rr;
                px[(size_t)row * 4096 + col] = acc[tm][tn][rr];
            }
        }
}

// ---------------- SPLIT kernel D: aph + adx/adh/adb; epilogue reads px slot then packs ----------------
// gates output is packed IN PLACE into the px slot just read: u32 = (hi16<<16)|lo16.
// Each (row,col) slot is read then written by exactly one thread -> race-free by construction.
// block 64x64, waves 2x2, wave 32x32, 4 acc sets
__global__ __launch_bounds__(256) void dgates(
    const u16* __restrict__ mh, const u16* __restrict__ hoc, const u16* __restrict__ rkT,
    const u16* __restrict__ dxc, const u16* __restrict__ dhc, const u16* __restrict__ dbc,
    uint32_t* pxgp,
    const void* __restrict__ bias, const void* __restrict__ dx_b,
    const void* __restrict__ dh_b, const void* __restrict__ db_b,
    const int* __restrict__ flag) {
    __shared__ __align__(16) u16 sA[64 * 40];
    __shared__ __align__(16) u16 sB1[64 * 40];
    __shared__ __align__(16) u16 sB2[64 * 40];
    __shared__ __align__(16) u16 sB3[64 * 40];
    int isbf = *flag;
    int tid = threadIdx.x, lane = tid & 63, wave = tid >> 6;
    int wm = (wave & 1) * 32, wn = (wave >> 1) * 32;
    int bm = blockIdx.y * 64, bn = blockIdx.x * 64;
    floatx4 aph[2][2] = {}, adx[2][2] = {}, adh[2][2] = {}, adb[2][2] = {};
    int mr = lane & 15, kq = (lane >> 4) * 8;
    // phase A: ph = mh @ rkT, K=1024
    for (int k0 = 0; k0 < 1024; k0 += 32) {
        stage_sync(sA,  mh,  bm, 1024, k0, 64, tid);
        stage_sync(sB1, rkT, bn, 1024, k0, 64, tid);
        __syncthreads();
        bf16x8 a[2], b[2];
        #pragma unroll
        for (int t = 0; t < 2; t++) {
            a[t] = *(const bf16x8*)&sA[(wm + t * 16 + mr) * 40 + kq];
            b[t] = *(const bf16x8*)&sB1[(wn + t * 16 + mr) * 40 + kq];
        }
        #pragma unroll
        for (int tm = 0; tm < 2; tm++)
            #pragma unroll
            for (int tn = 0; tn < 2; tn++)
                aph[tm][tn] = MFMA16(a[tm], b[tn], aph[tm][tn], 0, 0, 0);
        __syncthreads();
    }
    // phase B: d_* over K-concat 768: A=[hi|lo|hi], B=[Whi|Whi|Wlo]
    for (int k0 = 0; k0 < 768; k0 += 32) {
        stage_sync(sA,  hoc, bm, 768, k0, 64, tid);
        stage_sync(sB1, dxc, bn, 768, k0, 64, tid);
        stage_sync(sB2, dhc, bn, 768, k0, 64, tid);
        stage_sync(sB3, dbc, bn, 768, k0, 64, tid);
        __syncthreads();
        bf16x8 a[2], bx[2], bh[2], bb[2];
        #pragma unroll
        for (int t = 0; t < 2; t++) {
            int ra = (wm + t * 16 + mr) * 40 + kq;
            int rb = (wn + t * 16 + mr) * 40 + kq;
            a[t]  = *(const bf16x8*)&sA[ra];
            bx[t] = *(const bf16x8*)&sB1[rb];
            bh[t] = *(const bf16x8*)&sB2[rb];
            bb[t] = *(const bf16x8*)&sB3[rb];
        }
        #pragma unroll
        for (int tm = 0; tm < 2; tm++)
            #pragma unroll
            for (int tn = 0; tn < 2; tn++) {
                adx[tm][tn] = MFMA16(a[tm], bx[tn], adx[tm][tn], 0, 0, 0);
                adh[tm][tn] = MFMA16(a[tm], bh[tn], adh[tm][tn], 0, 0, 0);
                adb[tm][tn] = MFMA16(a[tm], bb[tn], adb[tm][tn], 0, 0, 0);
            }
        __syncthreads();
    }
    // epilogue: g = (adx+dxb)*(px+bv) + (adh+dhb)*aph + (adb+dbb); pack in place
    #pragma unroll
    for (int tm = 0; tm < 2; tm++)
        #pragma unroll
        for (int tn = 0; tn < 2; tn++) {
            int col = bn + wn + tn * 16 + (lane & 15);
            float bv  = ldmix(bias, col, isbf);
            float dxb = ldmix(dx_b, col, isbf);
            float dhb = ldmix(dh_b, col, isbf);
            float dbb = ldmix(db_b, col, isbf);
            #pragma unroll
            for (int rr = 0; rr < 4; rr++) {
                int row = bm + wm + tm * 16 + (lane >> 4) * 4 + rr;
                size_t idx = (size_t)row * 4096 + col;
                float pxv = u2f(pxgp[idx]) + bv;
                float ph = aph[tm][tn][rr];
                float dx = adx[tm][tn][rr] + dxb;
                float dh = adh[tm][tn][rr] + dhb;
                float db = adb[tm][tn][rr] + dbb;
                float g = dx * pxv + dh * ph + db;
                u16 hi = f2bf(g);
                u16 lo = f2bf(g - bf2f(hi));
                pxgp[idx] = ((uint32_t)hi << 16) | (uint32_t)lo;
            }
        }
}

// ---------------- FALLBACK fused mega (r4 geometry + padded LDS) ----------------
__global__ __launch_bounds__(256) void mega_fused(
    const u16* __restrict__ xh, const u16* __restrict__ xl, const u16* __restrict__ mh,
    const u16* __restrict__ hoc, const u16* __restrict__ kT, const u16* __restrict__ rkT,
    const u16* __restrict__ dxc, const u16* __restrict__ dhc, const u16* __restrict__ dbc,
    const void* __restrict__ bias, const void* __restrict__ dx_b,
    const void* __restrict__ dh_b, const void* __restrict__ db_b,
    u16* __restrict__ gp_hi, u16* __restrict__ gp_lo, const int* __restrict__ flag) {
    __shared__ __align__(16) u16 sA1[64 * 40];
    __shared__ __align__(16) u16 sA2[64 * 40];
    __shared__ __align__(16) u16 sA3[64 * 40];
    __shared__ __align__(16) u16 sB1[64 * 40];
    __shared__ __align__(16) u16 sB2[64 * 40];
    int isbf = *flag;
    int tid = threadIdx.x, lane = tid & 63, wave = tid >> 6;
    int wm = (wave & 1) * 32, wn = (wave >> 1) * 32;
    int bm = blockIdx.y * 64, bn = blockIdx.x * 64;
    floatx4 apx[2][2] = {}, aph[2][2] = {}, adx[2][2] = {}, adh[2][2] = {}, adb[2][2] = {};
    int mr = lane & 15, kq = (lane >> 4) * 8;
    for (int k0 = 0; k0 < 1024; k0 += 32) {
        stage_sync(sA1, xh,  bm, 1024, k0, 64, tid);
        stage_sync(sA2, xl,  bm, 1024, k0, 64, tid);
        stage_sync(sA3, mh,  bm, 1024, k0, 64, tid);
        stage_sync(sB1, kT,  bn, 1024, k0, 64, tid);
        stage_sync(sB2, rkT, bn, 1024, k0, 64, tid);
        __syncthreads();
        bf16x8 ah[2], al[2], am[2], bk[2], br[2];
        #pragma unroll
        for (int t = 0; t < 2; t++) {
            int ra = (wm + t * 16 + mr) * 40 + kq;
            int rb = (wn + t * 16 + mr) * 40 + kq;
            ah[t] = *(const bf16x8*)&sA1[ra];
            al[t] = *(const bf16x8*)&sA2[ra];
            am[t] = *(const bf16x8*)&sA3[ra];
            bk[t] = *(const bf16x8*)&sB1[rb];
            br[t] = *(const bf16x8*)&sB2[rb];
        }
        #pragma unroll
        for (int tm = 0; tm < 2; tm++)
            #pragma unroll
            for (int tn = 0; tn < 2; tn++) {
                apx[tm][tn] = MFMA16(ah[tm], bk[tn], apx[tm][tn], 0, 0, 0);
                apx[tm][tn] = MFMA16(al[tm], bk[tn], apx[tm][tn], 0, 0, 0);
                aph[tm][tn] = MFMA16(am[tm], br[tn], aph[tm][tn], 0, 0, 0);
            }
        __syncthreads();
    }
    for (int pa = 0; pa < 3; pa++) {
        int ka = (pa == 1) ? 256 : 0;
        int kb = (pa == 2) ? 256 : 0;
        for (int k0 = 0; k0 < 256; k0 += 32) {
            stage_sync(sA1, hoc, bm, 512, ka + k0, 64, tid);
            stage_sync(sB1, dxc, bn, 512, kb + k0, 64, tid);
            stage_sync(sB2, dhc, bn, 512, kb + k0, 64, tid);
            stage_sync(sA3, dbc, bn, 512, kb + k0, 64, tid);
            __syncthreads();
            bf16x8 a[2], bx[2], bh[2], bb[2];
            #pragma unroll
            for (int t = 0; t < 2; t++) {
                int ra = (wm + t * 16 + mr) * 40 + kq;
                int rb = (wn + t * 16 + mr) * 40 + kq;
                a[t]  = *(const bf16x8*)&sA1[ra];
                bx[t] = *(const bf16x8*)&sB1[rb];
                bh[t] = *(const bf16x8*)&sB2[rb];
                bb[t] = *(const bf16x8*)&sA3[rb];
            }
            #pragma unroll
            for (int tm = 0; tm < 2; tm++)
                #pragma unroll
                for (int tn = 0; tn < 2; tn++) {
                    adx[tm][tn] = MFMA16(a[tm], bx[tn], adx[tm][tn], 0, 0, 0);
                    adh[tm][tn] = MFMA16(a[tm], bh[tn], adh[tm][tn], 0, 0, 0);
                    adb[tm][tn] = MFMA16(a[tm], bb[tn], adb[tm][tn], 0, 0, 0);
                }
            __syncthreads();
        }
    }
    #pragma unroll
    for (int tm = 0; tm < 2; tm++)
        #pragma unroll
        for (int tn = 0; tn < 2; tn++) {
            int col = bn + wn + tn * 16 + (lane & 15);
            float bv  = ldmix(bias, col, isbf);
            float dxb = ldmix(dx_b, col, isbf);
            float dhb = ldmix(dh_b, col, isbf);
            float dbb = ldmix(db_b, col, isbf);
            #pragma unroll
            for (int rr = 0; rr < 4; rr++) {
                int row = bm + wm + tm * 16 + (lane >> 4) * 4 + rr;
                float pxv = apx[tm][tn][rr] + bv;
                float ph = aph[tm][tn][rr];
                float dx = adx[tm][tn][rr] + dxb;
                float dh = adh[tm][tn][rr] + dhb;
                float db = adb[tm][tn][rr] + dbb;
                float g = dx * pxv + dh * ph + db;
                u16 hi = f2bf(g);
                gp_hi[(size_t)row * 4096 + col] = hi;
                gp_lo[(size_t)row * 4096 + col] = f2bf(g - bf2f(hi));
            }
        }
}

// ---------------- LN + main cell ----------------
__device__ __forceinline__ void block_reduce2(float& a, float& b, float* red) {
    #pragma unroll
    for (int o = 32; o > 0; o >>= 1) {
        a += __shfl_down(a, o, 64);
        b += __shfl_down(b, o, 64);
    }
    int lane = threadIdx.x & 63, w = threadIdx.x >> 6;
    if (lane == 0) { red[w] = a; red[4 + w] = b; }
    __syncthreads();
    a = red[0] + red[1] + red[2] + red[3];
    b = red[4] + red[5] + red[6] + red[7];
    __syncthreads();
}

__device__ __forceinline__ void ln_body(float* sPre, float* sC, float* red,
                                        const void* main_c, void* out, int isbf,
                                        int b, int tid) {
    float s = 0.f, q = 0.f;
    for (int j = tid; j < 4096; j += 256) { float v = sPre[j]; s += v; q += v * v; }
    block_reduce2(s, q, red);
    float mean = s * (1.f / 4096.f);
    float var = q * (1.f / 4096.f) - mean * mean;
    float rs = rsqrtf(var + 1e-3f);
    float s2 = 0.f, q2 = 0.f;
    for (int u = tid; u < 1024; u += 256) {
        float gi = (sPre[u] - mean) * rs;
        float gf = (sPre[u + 1024] - mean) * rs;
        float gg = (sPre[u + 2048] - mean) * rs;
        float c = ldmix(main_c, (size_t)b * 1024 + u, isbf);
        float cn = sigf(gf) * c + sigf(gi) * tanhf(gg);
        sC[u] = cn;
        if (isbf) ((u16*)out)[O_C + (size_t)b * 1024 + u] = f2bf(cn);
        else      ((float*)out)[O_C + (size_t)b * 1024 + u] = cn;
        s2 += cn; q2 += cn * cn;
    }
    block_reduce2(s2, q2, red);
    float m2 = s2 * (1.f / 1024.f);
    float v2 = q2 * (1.f / 1024.f) - m2 * m2;
    float rs2 = rsqrtf(v2 + 1e-3f);
    for (int u = tid; u < 1024; u += 256) {
        float go = (sPre[u + 3072] - mean) * rs;
        float hn = sigf(go) * tanhf((sC[u] - m2) * rs2);
        if (isbf) ((u16*)out)[O_H + (size_t)b * 1024 + u] = f2bf(hn);
        else      ((float*)out)[O_H + (size_t)b * 1024 + u] = hn;
    }
}

__global__ __launch_bounds__(256) void ln_main(const u16* __restrict__ gp_hi,
                                               const u16* __restrict__ gp_lo,
                                               const void* __restrict__ main_c,
                                               void* __restrict__ out,
                                               const int* __restrict__ flag) {
    __shared__ float sPre[4096];
    __shared__ float sC[1024];
    __shared__ float red[8];
    int isbf = *flag;
    int b = blockIdx.x, tid = threadIdx.x;
    const u16* gh = gp_hi + (size_t)b * 4096;
    const u16* gl = gp_lo + (size_t)b * 4096;
    for (int j = tid; j < 4096; j += 256) sPre[j] = bf2f(gh[j]) + bf2f(gl[j]);
    __syncthreads();
    ln_body(sPre, sC, red, main_c, out, isbf, b, tid);
}

__global__ __launch_bounds__(256) void ln_packed(const uint32_t* __restrict__ gp32,
                                                 const void* __restrict__ main_c,
                                                 void* __restrict__ out,
                                                 const int* __restrict__ flag) {
    __shared__ float sPre[4096];
    __shared__ float sC[1024];
    __shared__ float red[8];
    int isbf = *flag;
    int b = blockIdx.x, tid = threadIdx.x;
    const uint32_t* gp = gp32 + (size_t)b * 4096;
    for (int j = tid; j < 4096; j += 256) {
        uint32_t w = gp[j];
        sPre[j] = bf2f((u16)(w >> 16)) + bf2f((u16)(w & 0xffff));
    }
    __syncthreads();
    ln_body(sPre, sC, red, main_c, out, isbf, b, tid);
}

// ---------------- launcher ----------------
extern "C" void kernel_launch(void* const* d_in, const int* in_sizes, int n_in,
                              void* d_out, int out_size, void* d_ws, size_t ws_size,
                              hipStream_t stream) {
    (void)in_sizes; (void)n_in; (void)out_size;
    const void* inputs   = d_in[0];
    const void* main_h   = d_in[1];
    const void* main_c   = d_in[2];
    const void* hyper_h  = d_in[3];
    const void* hyper_c  = d_in[4];
    const void* kernel_w = d_in[5];
    const void* rec_w    = d_in[6];
    const void* bias     = d_in[7];
    const void* hyper_k  = d_in[8];
    const void* hyper_rk = d_in[9];
    const void* hyper_b  = d_in[10];
    const void* dx_w = d_in[11];
    const void* dx_b = d_in[12];
    const void* dh_w = d_in[13];
    const void* dh_b = d_in[14];
    const void* db_w = d_in[15];
    const void* db_b = d_in[16];
    char* ws = (char*)d_ws;
    const size_t MB = 1024 * 1024;
    bool big = ws_size >= 100 * MB;  // split path needs 98.25 MB; fallback needs ~75.3 MB (proven)

    // shared prefix
    int* flag = (int*)ws;
    size_t off = 256;
    u16* xh = (u16*)(ws + off); off += 4 * MB;
    u16* xl = (u16*)(ws + off); off += 4 * MB;
    u16* mh = (u16*)(ws + off); off += 4 * MB;
    u16* hh = (u16*)(ws + off); off += 1 * MB;

    detect_dtype<<<1, 64, 0, stream>>>((const u16*)inputs, flag);
    cvt_all<<<2304, 256, 0, stream>>>(inputs, main_h, hyper_h, xh, xl, mh, hh, flag);

    dim3 tblk(32, 8);
    if (big) {
        // split layout: prefix 13.25 + hoc 3 + kT 8 + rkT 8 + d* 18 + px 32 + region 16 = 98.25 MB
        u16* hoc = (u16*)(ws + off); off += 3 * MB;                 // [2048,768] = [hi|lo|hi]
        u16* kT  = (u16*)(ws + off); off += 8 * MB;
        u16* rkT = (u16*)(ws + off); off += 8 * MB;
        u16* dxc = (u16*)(ws + off); off += 6 * MB;                 // [4096,768] = [Whi|Whi|Wlo]
        u16* dhc = (u16*)(ws + off); off += 6 * MB;
        u16* dbc = (u16*)(ws + off); off += 6 * MB;
        float* px = (float*)(ws + off); off += 32 * MB;             // [2048,4096] fp32, becomes gp32
        char* region = ws + off;                                    // 16 MB: BTh + zbuf
        u16* BTh = (u16*)region;                                    // [1024,2304] 4.5 MB
        float* zbuf = (float*)(region + (size_t)1024 * 2304 * 2);   // [2048,1024] 8 MB

        transpose_cvt2<<<dim3(32, 64), tblk, 0, stream>>>(hyper_k, BTh, nullptr, 2048, 1024, 2304, 0, flag);
        transpose_cvt2<<<dim3(32, 8),  tblk, 0, stream>>>(hyper_rk, BTh, nullptr, 256, 1024, 2304, 2048, flag);
        transpose_cvt2<<<dim3(128, 32), tblk, 0, stream>>>(kernel_w, kT, nullptr, 1024, 4096, 1024, 0, flag);
        transpose_cvt2<<<dim3(128, 32), tblk, 0, stream>>>(rec_w, rkT, nullptr, 1024, 4096, 1024, 0, flag);
        transpose_d<<<dim3(128, 8, 3), tblk, 0, stream>>>(dx_w, dh_w, db_w, dxc, dhc, dbc, 768, 1, flag);

        gemm_hyper<<<dim3(16, 16), 256, 0, stream>>>(xh, xl, mh, hh, BTh, zbuf);
        hyper_cell<<<2048, 256, 0, stream>>>(zbuf, hyper_c, hyper_b, d_out, hoc, 768, 1, flag);
        proj_px<<<dim3(32, 16), 256, 0, stream>>>(xh, xl, kT, px);
        // dgates reads px[idx] then packs gates into the SAME u32 slot (race-free in-place)
        dgates<<<dim3(64, 32), 256, 0, stream>>>(mh, hoc, rkT, dxc, dhc, dbc, (uint32_t*)px,
                                                 bias, dx_b, dh_b, db_b, flag);
        ln_packed<<<2048, 256, 0, stream>>>((const uint32_t*)px, main_c, d_out, flag);
    } else {
        // fallback layout (proven r4/r5-class budget ~75.3 MB)
        u16* hoc = (u16*)(ws + off); off += 2 * MB;                 // [2048,512] = [hi|lo]
        u16* kT  = (u16*)(ws + off); off += 8 * MB;
        u16* rkT = (u16*)(ws + off); off += 8 * MB;
        u16* dxc = (u16*)(ws + off); off += 4 * MB;                 // [4096,512] = [Whi|Wlo]
        u16* dhc = (u16*)(ws + off); off += 4 * MB;
        u16* dbc = (u16*)(ws + off); off += 4 * MB;
        char* region = ws + off;                                    // 32 MB double-use
        u16* BTh = (u16*)region;
        float* zbuf = (float*)(region + (size_t)1024 * 2304 * 2);
        u16* gphi = (u16*)region;                                   // 16 MB (after hyper phase)
        u16* gplo = (u16*)(region + (size_t)2048 * 4096 * 2);       // 16 MB

        transpose_cvt2<<<dim3(32, 64), tblk, 0, stream>>>(hyper_k, BTh, nullptr, 2048, 1024, 2304, 0, flag);
        transpose_cvt2<<<dim3(32, 8),  tblk, 0, stream>>>(hyper_rk, BTh, nullptr, 256, 1024, 2304, 2048, flag);
        transpose_cvt2<<<dim3(128, 32), tblk, 0, stream>>>(kernel_w, kT, nullptr, 1024, 4096, 1024, 0, flag);
        transpose_cvt2<<<dim3(128, 32), tblk, 0, stream>>>(rec_w, rkT, nullptr, 1024, 4096, 1024, 0, flag);
        transpose_d<<<dim3(128, 8, 3), tblk, 0, stream>>>(dx_w, dh_w, db_w, dxc, dhc, dbc, 512, 0, flag);

        gemm_hyper<<<dim3(16, 16), 256, 0, stream>>>(xh, xl, mh, hh, BTh, zbuf);
        hyper_cell<<<2048, 256, 0, stream>>>(zbuf, hyper_c, hyper_b, d_out, hoc, 512, 0, flag);
        mega_fused<<<dim3(64, 32), 256, 0, stream>>>(xh, xl, mh, hoc, kT, rkT, dxc, dhc, dbc,
                                                     bias, dx_b, dh_b, db_b, gphi, gplo, flag);
        ln_main<<<2048, 256, 0, stream>>>(gphi, gplo, main_c, d_out, flag);
    }
}

// Round 8
// 364.165 us; speedup vs baseline: 1.4110x; 1.2911x over previous
//
#include <hip/hip_runtime.h>
#include <cstdint>

typedef unsigned short u16;
typedef _Float16 half8 __attribute__((ext_vector_type(8)));
typedef float floatx4 __attribute__((ext_vector_type(4)));

#define BB 2048
#define UU 1024
#define HUx 256
#define O_H  0
#define O_C  (BB*UU)
#define O_HO (2*BB*UU)
#define O_HC (2*BB*UU + BB*HUx)
#define MFMAH __builtin_amdgcn_mfma_f32_16x16x32_f16

__device__ __forceinline__ float bf2f(u16 u) {
    union { uint32_t i; float f; } v; v.i = ((uint32_t)u) << 16; return v.f;
}
__device__ __forceinline__ u16 f2bf(float f) {
    union { float f; uint32_t i; } v; v.f = f;
    uint32_t r = v.i + 0x7fffu + ((v.i >> 16) & 1u);
    return (u16)(r >> 16);
}
__device__ __forceinline__ u16 f2h(float f) {
    _Float16 h = (_Float16)f; u16 u; __builtin_memcpy(&u, &h, 2); return u;
}
__device__ __forceinline__ float sigf(float x) { return 1.f / (1.f + expf(-x)); }
__device__ __forceinline__ float ldmix(const void* p, size_t i, int isbf) {
    return isbf ? bf2f(((const u16*)p)[i]) : ((const float*)p)[i];
}
// load input element (bf16 or fp32) -> fp16 bits
__device__ __forceinline__ u16 ld2h(const void* p, size_t i, int isbf) {
    return f2h(ldmix(p, i, isbf));
}

// sync staged copy: rows x 32 fp16 tile from src(row0.., k0..) into padded LDS [rows][40]
// stride 40 u16 = 80 B (16B-aligned rows, 20-bank stride -> even bank spread; proven r7)
__device__ __forceinline__ void stage_sync(u16* lds, const u16* src, int row0, int ldK,
                                           int k0, int rows, int tid) {
    for (int v = tid; v < rows * 4; v += 256) {
        int r = v >> 2, c = (v & 3) * 8;
        half8 d = *(const half8*)(src + (size_t)(row0 + r) * ldK + k0 + c);
        *(half8*)&lds[r * 40 + c] = d;
    }
}

// ---------------- dtype detection (1 = bf16, 0 = fp32) ----------------
__global__ void detect_dtype(const u16* __restrict__ raw, int* __restrict__ flag) {
    u16 u = raw[2 * threadIdx.x];
    int e = (u >> 7) & 0xFF;
    unsigned long long m = __ballot(e >= 100 && e <= 134);
    if (threadIdx.x == 0) *flag = (__popcll(m) >= 32) ? 1 : 0;
}

// ---------------- merged input conversion -> fp16: inputs->xh, main_h->mh, hyper_h->hh ----------------
__global__ void cvt_all(const void* __restrict__ xs, const void* __restrict__ ms,
                        const void* __restrict__ hs, u16* __restrict__ xh,
                        u16* __restrict__ mh, u16* __restrict__ hh, const int* __restrict__ flag) {
    int i = blockIdx.x * 256 + threadIdx.x;
    int isbf = *flag;
    const void* src; u16* dst; int t;
    if (i < 262144)      { src = xs; dst = xh; t = i; }
    else if (i < 524288) { src = ms; dst = mh; t = i - 262144; }
    else                 { src = hs; dst = hh; t = i - 524288; }  // < 65536
    #pragma unroll
    for (int j = 0; j < 8; j++)
        dst[(size_t)t * 8 + j] = ld2h(src, (size_t)t * 8 + j, isbf);
}

// ---------------- transpose(+convert->fp16): out[c*ostride+ocol+r]=in[r*C+c] ----------------
__global__ void transpose_cvt(const void* __restrict__ in, u16* __restrict__ out,
                              int R, int C, int ostride, int ocol,
                              const int* __restrict__ flag) {
    __shared__ u16 th[32][33];
    int isbf = *flag;
    int c0 = blockIdx.x * 32, r0 = blockIdx.y * 32;
    int tx = threadIdx.x, ty = threadIdx.y;  // block (32,8)
    #pragma unroll
    for (int i = 0; i < 32; i += 8)
        th[ty + i][tx] = ld2h(in, (size_t)(r0 + ty + i) * C + c0 + tx, isbf);
    __syncthreads();
    #pragma unroll
    for (int i = 0; i < 32; i += 8)
        out[(size_t)(c0 + ty + i) * ostride + ocol + r0 + tx] = th[tx][ty + i];
}

// z-dim variant: up to 3 (in,out) pairs with identical geometry
__global__ void transpose_z(const void* __restrict__ i0, const void* __restrict__ i1,
                            const void* __restrict__ i2, u16* __restrict__ o0,
                            u16* __restrict__ o1, u16* __restrict__ o2,
                            int R, int C, int ostride, const int* __restrict__ flag) {
    __shared__ u16 th[32][33];
    const void* in = (blockIdx.z == 0) ? i0 : (blockIdx.z == 1) ? i1 : i2;
    u16* out = (blockIdx.z == 0) ? o0 : (blockIdx.z == 1) ? o1 : o2;
    int isbf = *flag;
    int c0 = blockIdx.x * 32, r0 = blockIdx.y * 32;
    int tx = threadIdx.x, ty = threadIdx.y;
    #pragma unroll
    for (int i = 0; i < 32; i += 8)
        th[ty + i][tx] = ld2h(in, (size_t)(r0 + ty + i) * C + c0 + tx, isbf);
    __syncthreads();
    #pragma unroll
    for (int i = 0; i < 32; i += 8)
        out[(size_t)(c0 + ty + i) * ostride + r0 + tx] = th[tx][ty + i];
}

// ---------------- hyper GEMM (fp16): z = x@Wx + mh@Wm + hh@Wh ----------------
// block 128M x 64N, waves 2x2, wave 64x32; BK=32 padded LDS (proven r7 layout)
__global__ __launch_bounds__(256) void gemm_hyper(const u16* __restrict__ xh,
                                                  const u16* __restrict__ mh,
                                                  const u16* __restrict__ hh,
                                                  const u16* __restrict__ BT,
                                                  float* __restrict__ z) {
    __shared__ __align__(16) u16 sA[128 * 40];
    __shared__ __align__(16) u16 sB[64 * 40];
    int tid = threadIdx.x, lane = tid & 63, wave = tid >> 6;
    int wm = (wave & 1) * 64, wn = (wave >> 1) * 32;
    int bm = blockIdx.y * 128, bn = blockIdx.x * 64;
    floatx4 acc[4][2] = {};
    int mr = lane & 15, kq = (lane >> 4) * 8;
    #pragma unroll 1
    for (int ph = 0; ph < 3; ph++) {
        const u16* Ap = (ph == 0) ? xh : (ph == 1) ? mh : hh;
        int ldA  = (ph == 2) ? 256 : 1024;
        int K    = (ph == 2) ? 256 : 1024;
        int koff = ph * 1024;  // 0, 1024, 2048
        for (int k0 = 0; k0 < K; k0 += 32) {
            stage_sync(sA, Ap, bm, ldA, k0, 128, tid);
            stage_sync(sB, BT, bn, 2304, koff + k0, 64, tid);
            __syncthreads();
            half8 a[4], b[2];
            #pragma unroll
            for (int t = 0; t < 4; t++) a[t] = *(const half8*)&sA[(wm + t * 16 + mr) * 40 + kq];
            #pragma unroll
            for (int t = 0; t < 2; t++) b[t] = *(const half8*)&sB[(wn + t * 16 + mr) * 40 + kq];
            #pragma unroll
            for (int tm = 0; tm < 4; tm++)
                #pragma unroll
                for (int tn = 0; tn < 2; tn++)
                    acc[tm][tn] = MFMAH(a[tm], b[tn], acc[tm][tn], 0, 0, 0);
            __syncthreads();
        }
    }
    #pragma unroll
    for (int tm = 0; tm < 4; tm++)
        #pragma unroll
        for (int tn = 0; tn < 2; tn++) {
            int col = bn + wn + tn * 16 + (lane & 15);
            #pragma unroll
            for (int rr = 0; rr < 4; rr++) {
                int row = bm + wm + tm * 16 + (lane >> 4) * 4 + rr;
                z[(size_t)row * 1024 + col] = acc[tm][tn][rr];
            }
        }
}

// ---------------- hyper LSTM cell; ho stored fp16 ----------------
__global__ void hyper_cell(const float* __restrict__ z, const void* __restrict__ hyper_c,
                           const void* __restrict__ hyper_bias, void* __restrict__ out,
                           u16* __restrict__ ho16, const int* __restrict__ flag) {
    int isbf = *flag;
    int t = blockIdx.x * 256 + threadIdx.x;
    int k = t & 255;
    const float* zr = z + (size_t)(t >> 8) * 1024;
    float hi = zr[k]       + ldmix(hyper_bias, k, isbf);
    float hf = zr[k + 256] + ldmix(hyper_bias, k + 256, isbf);
    float hg = zr[k + 512] + ldmix(hyper_bias, k + 512, isbf);
    float ho = zr[k + 768] + ldmix(hyper_bias, k + 768, isbf);
    float c  = ldmix(hyper_c, t, isbf);
    float cn = sigf(hf) * c + sigf(hi) * tanhf(hg);
    float hout = sigf(ho) * tanhf(cn);
    ho16[t] = f2h(hout);
    if (isbf) {
        ((u16*)out)[O_HO + t] = f2bf(hout);
        ((u16*)out)[O_HC + t] = f2bf(cn);
    } else {
        ((float*)out)[O_HO + t] = hout;
        ((float*)out)[O_HC + t] = cn;
    }
}

// ---------------- fused gates GEMM (fp16, 5 acc sets) -> gates_pre fp32 ----------------
// block 64x64, waves 2x2, wave 32x32; phase1 K=1024 (apx, aph), phase2 K=256 (adx, adh, adb)
__global__ __launch_bounds__(256) void mega_fused(
    const u16* __restrict__ xh, const u16* __restrict__ mh, const u16* __restrict__ ho16,
    const u16* __restrict__ kT, const u16* __restrict__ rkT,
    const u16* __restrict__ dxT, const u16* __restrict__ dhT, const u16* __restrict__ dbT,
    const void* __restrict__ bias, const void* __restrict__ dx_b,
    const void* __restrict__ dh_b, const void* __restrict__ db_b,
    float* __restrict__ gp, const int* __restrict__ flag) {
    __shared__ __align__(16) u16 sA1[64 * 40];
    __shared__ __align__(16) u16 sA2[64 * 40];
    __shared__ __align__(16) u16 sB1[64 * 40];
    __shared__ __align__(16) u16 sB2[64 * 40];
    __shared__ __align__(16) u16 sB3[64 * 40];
    int isbf = *flag;
    int tid = threadIdx.x, lane = tid & 63, wave = tid >> 6;
    int wm = (wave & 1) * 32, wn = (wave >> 1) * 32;
    int bm = blockIdx.y * 64, bn = blockIdx.x * 64;
    floatx4 apx[2][2] = {}, aph[2][2] = {}, adx[2][2] = {}, adh[2][2] = {}, adb[2][2] = {};
    int mr = lane & 15, kq = (lane >> 4) * 8;
    // phase 1: px = x@kT, ph = mh@rkT  (K=1024)
    for (int k0 = 0; k0 < 1024; k0 += 32) {
        stage_sync(sA1, xh,  bm, 1024, k0, 64, tid);
        stage_sync(sA2, mh,  bm, 1024, k0, 64, tid);
        stage_sync(sB1, kT,  bn, 1024, k0, 64, tid);
        stage_sync(sB2, rkT, bn, 1024, k0, 64, tid);
        __syncthreads();
        half8 ax[2], am[2], bk[2], br[2];
        #pragma unroll
        for (int t = 0; t < 2; t++) {
            int ra = (wm + t * 16 + mr) * 40 + kq;
            int rb = (wn + t * 16 + mr) * 40 + kq;
            ax[t] = *(const half8*)&sA1[ra];
            am[t] = *(const half8*)&sA2[ra];
            bk[t] = *(const half8*)&sB1[rb];
            br[t] = *(const half8*)&sB2[rb];
        }
        #pragma unroll
        for (int tm = 0; tm < 2; tm++)
            #pragma unroll
            for (int tn = 0; tn < 2; tn++) {
                apx[tm][tn] = MFMAH(ax[tm], bk[tn], apx[tm][tn], 0, 0, 0);
                aph[tm][tn] = MFMAH(am[tm], br[tn], aph[tm][tn], 0, 0, 0);
            }
        __syncthreads();
    }
    // phase 2: d_* = ho @ {dxT,dhT,dbT}  (K=256)
    for (int k0 = 0; k0 < 256; k0 += 32) {
        stage_sync(sA1, ho16, bm, 256, k0, 64, tid);
        stage_sync(sB1, dxT,  bn, 256, k0, 64, tid);
        stage_sync(sB2, dhT,  bn, 256, k0, 64, tid);
        stage_sync(sB3, dbT,  bn, 256, k0, 64, tid);
        __syncthreads();
        half8 a[2], bx[2], bh[2], bb[2];
        #pragma unroll
        for (int t = 0; t < 2; t++) {
            int ra = (wm + t * 16 + mr) * 40 + kq;
            int rb = (wn + t * 16 + mr) * 40 + kq;
            a[t]  = *(const half8*)&sA1[ra];
            bx[t] = *(const half8*)&sB1[rb];
            bh[t] = *(const half8*)&sB2[rb];
            bb[t] = *(const half8*)&sB3[rb];
        }
        #pragma unroll
        for (int tm = 0; tm < 2; tm++)
            #pragma unroll
            for (int tn = 0; tn < 2; tn++) {
                adx[tm][tn] = MFMAH(a[tm], bx[tn], adx[tm][tn], 0, 0, 0);
                adh[tm][tn] = MFMAH(a[tm], bh[tn], adh[tm][tn], 0, 0, 0);
                adb[tm][tn] = MFMAH(a[tm], bb[tn], adb[tm][tn], 0, 0, 0);
            }
        __syncthreads();
    }
    // epilogue: g = (adx+dxb)*(apx+bias) + (adh+dhb)*aph + (adb+dbb)
    #pragma unroll
    for (int tm = 0; tm < 2; tm++)
        #pragma unroll
        for (int tn = 0; tn < 2; tn++) {
            int col = bn + wn + tn * 16 + (lane & 15);
            float bv  = ldmix(bias, col, isbf);
            float dxb = ldmix(dx_b, col, isbf);
            float dhb = ldmix(dh_b, col, isbf);
            float dbb = ldmix(db_b, col, isbf);
            #pragma unroll
            for (int rr = 0; rr < 4; rr++) {
                int row = bm + wm + tm * 16 + (lane >> 4) * 4 + rr;
                float px = apx[tm][tn][rr] + bv;
                float ph = aph[tm][tn][rr];
                float dx = adx[tm][tn][rr] + dxb;
                float dh = adh[tm][tn][rr] + dhb;
                float db = adb[tm][tn][rr] + dbb;
                gp[(size_t)row * 4096 + col] = dx * px + dh * ph + db;
            }
        }
}

// ---------------- LN(4096) -> gates -> c_new -> LN(1024) -> h_new ----------------
__device__ __forceinline__ void block_reduce2(float& a, float& b, float* red) {
    #pragma unroll
    for (int o = 32; o > 0; o >>= 1) {
        a += __shfl_down(a, o, 64);
        b += __shfl_down(b, o, 64);
    }
    int lane = threadIdx.x & 63, w = threadIdx.x >> 6;
    if (lane == 0) { red[w] = a; red[4 + w] = b; }
    __syncthreads();
    a = red[0] + red[1] + red[2] + red[3];
    b = red[4] + red[5] + red[6] + red[7];
    __syncthreads();
}

__global__ __launch_bounds__(256) void ln_main(const float* __restrict__ gp,
                                               const void* __restrict__ main_c,
                                               void* __restrict__ out,
                                               const int* __restrict__ flag) {
    __shared__ float sPre[4096];
    __shared__ float sC[1024];
    __shared__ float red[8];
    int isbf = *flag;
    int b = blockIdx.x, tid = threadIdx.x;
    const float* g = gp + (size_t)b * 4096;
    float s = 0.f, q = 0.f;
    for (int j = tid; j < 4096; j += 256) {
        float v = g[j];
        sPre[j] = v; s += v; q += v * v;
    }
    block_reduce2(s, q, red);
    float mean = s * (1.f / 4096.f);
    float var = q * (1.f / 4096.f) - mean * mean;
    float rs = rsqrtf(var + 1e-3f);
    float s2 = 0.f, q2 = 0.f;
    for (int u = tid; u < 1024; u += 256) {
        float gi = (sPre[u] - mean) * rs;
        float gf = (sPre[u + 1024] - mean) * rs;
        float gg = (sPre[u + 2048] - mean) * rs;
        float c = ldmix(main_c, (size_t)b * 1024 + u, isbf);
        float cn = sigf(gf) * c + sigf(gi) * tanhf(gg);
        sC[u] = cn;
        if (isbf) ((u16*)out)[O_C + (size_t)b * 1024 + u] = f2bf(cn);
        else      ((float*)out)[O_C + (size_t)b * 1024 + u] = cn;
        s2 += cn; q2 += cn * cn;
    }
    block_reduce2(s2, q2, red);
    float m2 = s2 * (1.f / 1024.f);
    float v2 = q2 * (1.f / 1024.f) - m2 * m2;
    float rs2 = rsqrtf(v2 + 1e-3f);
    for (int u = tid; u < 1024; u += 256) {
        float go = (sPre[u + 3072] - mean) * rs;
        float hn = sigf(go) * tanhf((sC[u] - m2) * rs2);
        if (isbf) ((u16*)out)[O_H + (size_t)b * 1024 + u] = f2bf(hn);
        else      ((float*)out)[O_H + (size_t)b * 1024 + u] = hn;
    }
}

// ---------------- launcher ----------------
extern "C" void kernel_launch(void* const* d_in, const int* in_sizes, int n_in,
                              void* d_out, int out_size, void* d_ws, size_t ws_size,
                              hipStream_t stream) {
    (void)in_sizes; (void)n_in; (void)out_size; (void)ws_size;
    const void* inputs   = d_in[0];
    const void* main_h   = d_in[1];
    const void* main_c   = d_in[2];
    const void* hyper_h  = d_in[3];
    const void* hyper_c  = d_in[4];
    const void* kernel_w = d_in[5];
    const void* rec_w    = d_in[6];
    const void* bias     = d_in[7];
    const void* hyper_k  = d_in[8];
    const void* hyper_rk = d_in[9];
    const void* hyper_b  = d_in[10];
    const void* dx_w = d_in[11];
    const void* dx_b = d_in[12];
    const void* dh_w = d_in[13];
    const void* dh_b = d_in[14];
    const void* db_w = d_in[15];
    const void* db_b = d_in[16];
    char* ws = (char*)d_ws;
    const size_t MB = 1024 * 1024;

    // workspace layout: 76.75 MB total, NO overlays (ws >= 100 MB proven in r6/r7)
    int* flag = (int*)ws;
    size_t off = 256;
    u16* xh  = (u16*)(ws + off); off += 4 * MB;            // [2048,1024] fp16
    u16* mh  = (u16*)(ws + off); off += 4 * MB;            // [2048,1024] fp16
    u16* hh  = (u16*)(ws + off); off += 1 * MB;            // [2048,256]  fp16
    u16* ho  = (u16*)(ws + off); off += 1 * MB;            // [2048,256]  fp16
    u16* kT  = (u16*)(ws + off); off += 8 * MB;            // [4096,1024] fp16
    u16* rkT = (u16*)(ws + off); off += 8 * MB;            // [4096,1024] fp16
    u16* dxT = (u16*)(ws + off); off += 2 * MB;            // [4096,256]  fp16
    u16* dhT = (u16*)(ws + off); off += 2 * MB;
    u16* dbT = (u16*)(ws + off); off += 2 * MB;
    u16* BTh = (u16*)(ws + off); off += (size_t)1024 * 2304 * 2;  // 4.5 MB
    float* zbuf = (float*)(ws + off); off += 8 * MB;       // [2048,1024] fp32
    float* gp   = (float*)(ws + off); off += 32 * MB;      // [2048,4096] fp32

    detect_dtype<<<1, 64, 0, stream>>>((const u16*)inputs, flag);
    cvt_all<<<2304, 256, 0, stream>>>(inputs, main_h, hyper_h, xh, mh, hh, flag);

    dim3 tblk(32, 8);
    transpose_cvt<<<dim3(32, 64), tblk, 0, stream>>>(hyper_k, BTh, 2048, 1024, 2304, 0, flag);
    transpose_cvt<<<dim3(32, 8),  tblk, 0, stream>>>(hyper_rk, BTh, 256, 1024, 2304, 2048, flag);
    transpose_z<<<dim3(128, 32, 2), tblk, 0, stream>>>(kernel_w, rec_w, rec_w,
                                                       kT, rkT, rkT, 1024, 4096, 1024, flag);
    transpose_z<<<dim3(128, 8, 3), tblk, 0, stream>>>(dx_w, dh_w, db_w,
                                                      dxT, dhT, dbT, 256, 4096, 256, flag);

    gemm_hyper<<<dim3(16, 16), 256, 0, stream>>>(xh, mh, hh, BTh, zbuf);
    hyper_cell<<<2048, 256, 0, stream>>>(zbuf, hyper_c, hyper_b, d_out, ho, flag);
    mega_fused<<<dim3(64, 32), 256, 0, stream>>>(xh, mh, ho, kT, rkT, dxT, dhT, dbT,
                                                 bias, dx_b, dh_b, db_b, gp, flag);
    ln_main<<<2048, 256, 0, stream>>>(gp, main_c, d_out, flag);
}